// Round 1
// baseline (885.832 us; speedup 1.0000x reference)
//
#include <hip/hip_runtime.h>

#define BLOCK 256

// dot of 4 consecutive elems of array X_ (compile-time base 4*J_) with float4 W_
#define DOT4(X_, J_, W_) (X_[4*(J_)]*W_.x + X_[4*(J_)+1]*W_.y + X_[4*(J_)+2]*W_.z + X_[4*(J_)+3]*W_.w)

__launch_bounds__(BLOCK, 1)
__global__ void msfe_kernel(
    const float* __restrict__ f1, const float* __restrict__ f4, const float* __restrict__ fD,
    const float* __restrict__ Wp, const float* __restrict__ bp,
    const float* __restrict__ ln_g, const float* __restrict__ ln_b,
    const float* __restrict__ Wq, const float* __restrict__ bq,
    const float* __restrict__ Wk, const float* __restrict__ bk,
    const float* __restrict__ Wv, const float* __restrict__ bv,
    const float* __restrict__ Wo1, const float* __restrict__ bo1,
    const float* __restrict__ Wo2, const float* __restrict__ bo2,
    float* __restrict__ out, int nRows)
{
    __shared__ float Wp_l[32 * 256];
    __shared__ float Wq_l[1024], Wk_l[1024], Wv_l[1024], Wo1_l[1024], Wo2_l[1024];
    __shared__ float bp_l[32], g_l[32], b_l[32], bq_l[32], bk_l[32], bv_l[32], bo1_l[32], bo2_l[32];

    const int tid = threadIdx.x;

    // ---- stage all weights into LDS (coalesced float4) ----
    for (int i = tid; i < 2048; i += BLOCK)
        ((float4*)Wp_l)[i] = ((const float4*)Wp)[i];
    if (tid < 256) {
        ((float4*)Wq_l)[tid]  = ((const float4*)Wq)[tid];
        ((float4*)Wk_l)[tid]  = ((const float4*)Wk)[tid];
        ((float4*)Wv_l)[tid]  = ((const float4*)Wv)[tid];
        ((float4*)Wo1_l)[tid] = ((const float4*)Wo1)[tid];
        ((float4*)Wo2_l)[tid] = ((const float4*)Wo2)[tid];
    }
    if (tid < 32) {
        bp_l[tid] = bp[tid];  g_l[tid]  = ln_g[tid]; b_l[tid]  = ln_b[tid];
        bq_l[tid] = bq[tid];  bk_l[tid] = bk[tid];   bv_l[tid] = bv[tid];
        bo1_l[tid] = bo1[tid]; bo2_l[tid] = bo2[tid];
    }
    __syncthreads();

    const long row = (long)blockIdx.x * BLOCK + tid;
    if (row >= nRows) return;

    const float* __restrict__ p0 = f1 + row * 256;
    const float* __restrict__ p1 = f4 + row * 256;
    const float* __restrict__ p2 = fD + row * 256;

    // ---- Phase A: h[s][d] = f_s . Wp[d,:]  (96 accumulators) ----
    float acc0[32], acc1[32], acc2[32];
    #pragma unroll
    for (int d = 0; d < 32; ++d) { acc0[d] = 0.f; acc1[d] = 0.f; acc2[d] = 0.f; }

    #pragma unroll 1
    for (int kc = 0; kc < 256; kc += 32) {
        float4 a0[8], a1[8], a2[8];
        #pragma unroll
        for (int j = 0; j < 8; ++j) {
            a0[j] = *(const float4*)(p0 + kc + 4 * j);
            a1[j] = *(const float4*)(p1 + kc + 4 * j);
            a2[j] = *(const float4*)(p2 + kc + 4 * j);
        }
        #pragma unroll
        for (int d = 0; d < 32; ++d) {
            const float4* wrow = (const float4*)&Wp_l[d * 256 + kc];
            #pragma unroll
            for (int j = 0; j < 8; ++j) {
                float4 w = wrow[j];
                acc0[d] += a0[j].x * w.x + a0[j].y * w.y + a0[j].z * w.z + a0[j].w * w.w;
                acc1[d] += a1[j].x * w.x + a1[j].y * w.y + a1[j].z * w.z + a1[j].w * w.w;
                acc2[d] += a2[j].x * w.x + a2[j].y * w.y + a2[j].z * w.z + a2[j].w * w.w;
            }
        }
    }

    // ---- relu + LayerNorm -> X[3][32] ----
    float X[3][32];
#define LNORM(ACC_, S_)                                                              \
    {                                                                                \
        float sum = 0.f, sq = 0.f;                                                   \
        _Pragma("unroll")                                                            \
        for (int d = 0; d < 32; ++d) {                                               \
            float h = fmaxf(ACC_[d] + bp_l[d], 0.f);                                 \
            ACC_[d] = h; sum += h; sq += h * h;                                      \
        }                                                                            \
        float mu  = sum * 0.03125f;                                                  \
        float var = sq * 0.03125f - mu * mu;                                         \
        float inv = rsqrtf(var + 1e-5f);                                             \
        _Pragma("unroll")                                                            \
        for (int d = 0; d < 32; ++d)                                                 \
            X[S_][d] = g_l[d] * (ACC_[d] - mu) * inv + b_l[d];                       \
    }
    LNORM(acc0, 0)
    LNORM(acc1, 1)
    LNORM(acc2, 2)
#undef LNORM

    // ---- K[t][d] = bk[d] + X[t] . Wk[d,:] ----
    float K3[3][32];
    #pragma unroll
    for (int d = 0; d < 32; ++d) {
        const float4* wr = (const float4*)&Wk_l[d * 32];
        float s0 = bk_l[d], s1 = s0, s2 = s0;
        #pragma unroll
        for (int j = 0; j < 8; ++j) {
            float4 w = wr[j];
            s0 += DOT4(X[0], j, w);
            s1 += DOT4(X[1], j, w);
            s2 += DOT4(X[2], j, w);
        }
        K3[0][d] = s0; K3[1][d] = s1; K3[2][d] = s2;
    }

    // ---- per-s: Q, scores, softmax; accumulate g[t] = sum_s w[s][t] ----
    float g0 = 0.f, g1 = 0.f, g2 = 0.f;
    const float isq = 0.17677669529663688f; // 1/sqrt(32)
    #pragma unroll
    for (int s = 0; s < 3; ++s) {
        float Qs[32];
        #pragma unroll
        for (int d = 0; d < 32; ++d) {
            const float4* wr = (const float4*)&Wq_l[d * 32];
            float q = bq_l[d];
            #pragma unroll
            for (int j = 0; j < 8; ++j) {
                float4 w = wr[j];
                q += DOT4(X[s], j, w);
            }
            Qs[d] = q;
        }
        float sc0 = 0.f, sc1 = 0.f, sc2 = 0.f;
        #pragma unroll
        for (int d = 0; d < 32; ++d) {
            sc0 += Qs[d] * K3[0][d];
            sc1 += Qs[d] * K3[1][d];
            sc2 += Qs[d] * K3[2][d];
        }
        sc0 *= isq; sc1 *= isq; sc2 *= isq;
        float m  = fmaxf(sc0, fmaxf(sc1, sc2));
        float e0 = __expf(sc0 - m), e1 = __expf(sc1 - m), e2 = __expf(sc2 - m);
        float r  = 1.f / (e0 + e1 + e2);
        g0 += e0 * r; g1 += e1 * r; g2 += e2 * r;
    }
    g0 *= (1.f / 3.f); g1 *= (1.f / 3.f); g2 *= (1.f / 3.f);

    // pooled = (g0*X0 + g1*X1 + g2*X2) @ Wv^T + bv   (since sum_t g_t == 1)
    float xb[32];
    #pragma unroll
    for (int e = 0; e < 32; ++e)
        xb[e] = g0 * X[0][e] + g1 * X[1][e] + g2 * X[2][e];

    float pooled[32];
    #pragma unroll
    for (int d = 0; d < 32; ++d) {
        const float4* wr = (const float4*)&Wv_l[d * 32];
        float p = bv_l[d];
        #pragma unroll
        for (int j = 0; j < 8; ++j) {
            float4 w = wr[j];
            p += DOT4(xb, j, w);
        }
        pooled[d] = p;
    }

    // out = relu(pooled @ Wo1^T + bo1) @ Wo2^T + bo2 + pooled
    float h1[32];
    #pragma unroll
    for (int d = 0; d < 32; ++d) {
        const float4* wr = (const float4*)&Wo1_l[d * 32];
        float h = bo1_l[d];
        #pragma unroll
        for (int j = 0; j < 8; ++j) {
            float4 w = wr[j];
            h += DOT4(pooled, j, w);
        }
        h1[d] = fmaxf(h, 0.f);
    }

    float o[32];
    #pragma unroll
    for (int d = 0; d < 32; ++d) {
        const float4* wr = (const float4*)&Wo2_l[d * 32];
        float v = bo2_l[d] + pooled[d];
        #pragma unroll
        for (int j = 0; j < 8; ++j) {
            float4 w = wr[j];
            v += DOT4(h1, j, w);
        }
        o[d] = v;
    }

    float4* op = (float4*)(out + row * 32);
    #pragma unroll
    for (int j = 0; j < 8; ++j)
        op[j] = make_float4(o[4 * j], o[4 * j + 1], o[4 * j + 2], o[4 * j + 3]);
}

extern "C" void kernel_launch(void* const* d_in, const int* in_sizes, int n_in,
                              void* d_out, int out_size, void* d_ws, size_t ws_size,
                              hipStream_t stream) {
    const float* f1   = (const float*)d_in[0];
    const float* f4   = (const float*)d_in[1];
    const float* fD   = (const float*)d_in[2];
    const float* Wp   = (const float*)d_in[3];
    const float* bp   = (const float*)d_in[4];
    const float* ln_g = (const float*)d_in[5];
    const float* ln_b = (const float*)d_in[6];
    const float* Wq   = (const float*)d_in[7];
    const float* bq   = (const float*)d_in[8];
    const float* Wk   = (const float*)d_in[9];
    const float* bk   = (const float*)d_in[10];
    const float* Wv   = (const float*)d_in[11];
    const float* bv   = (const float*)d_in[12];
    const float* Wo1  = (const float*)d_in[13];
    const float* bo1  = (const float*)d_in[14];
    const float* Wo2  = (const float*)d_in[15];
    const float* bo2  = (const float*)d_in[16];

    const int nRows  = in_sizes[0] / 256;
    const int blocks = (nRows + BLOCK - 1) / BLOCK;

    msfe_kernel<<<blocks, BLOCK, 0, stream>>>(
        f1, f4, fD, Wp, bp, ln_g, ln_b, Wq, bq, Wk, bk, Wv, bv,
        Wo1, bo1, Wo2, bo2, (float*)d_out, nRows);
}

// Round 2
// 481.002 us; speedup vs baseline: 1.8416x; 1.8416x over previous
//
#include <hip/hip_runtime.h>

#define BLOCK 256
#define RPB 128   // rows per block (2 threads per row)

// dot of float4 W_ with 4 consecutive elems of X_ starting at 4*J_
#define DOT4(X_, J_, W_) (X_[4*(J_)]*W_.x + X_[4*(J_)+1]*W_.y + X_[4*(J_)+2]*W_.z + X_[4*(J_)+3]*W_.w)

__launch_bounds__(BLOCK, 2)
__global__ void msfe_kernel(
    const float* __restrict__ f1, const float* __restrict__ f4, const float* __restrict__ fD,
    const float* __restrict__ Wp, const float* __restrict__ bp,
    const float* __restrict__ ln_g, const float* __restrict__ ln_b,
    const float* __restrict__ Wq, const float* __restrict__ bq,
    const float* __restrict__ Wk, const float* __restrict__ bk,
    const float* __restrict__ Wv, const float* __restrict__ bv,
    const float* __restrict__ Wo1, const float* __restrict__ bo1,
    const float* __restrict__ Wo2, const float* __restrict__ bo2,
    float* __restrict__ out, int nRows)
{
    __shared__ float Wp_l[8192];
    __shared__ float Wq_l[1024], Wk_l[1024], A_l[1024];
    __shared__ float Wv_l[1024], Wo1_l[1024], Wo2_l[1024];
    __shared__ float bp_l[32], g_l[32], b_l[32], u_l[32], v_l[32];
    __shared__ float bv_l[32], bo1_l[32], bo2_l[32];
    __shared__ float c_l;

    const int tid = threadIdx.x;

    // ---- stage weights (coalesced float4) ----
    #pragma unroll
    for (int i = 0; i < 8; ++i)
        ((float4*)Wp_l)[tid + i * BLOCK] = ((const float4*)Wp)[tid + i * BLOCK];
    ((float4*)Wq_l)[tid]  = ((const float4*)Wq)[tid];
    ((float4*)Wk_l)[tid]  = ((const float4*)Wk)[tid];
    ((float4*)Wv_l)[tid]  = ((const float4*)Wv)[tid];
    ((float4*)Wo1_l)[tid] = ((const float4*)Wo1)[tid];
    ((float4*)Wo2_l)[tid] = ((const float4*)Wo2)[tid];
    if (tid < 32) {
        bp_l[tid] = bp[tid]; g_l[tid] = ln_g[tid]; b_l[tid] = ln_b[tid];
        bv_l[tid] = bv[tid]; bo1_l[tid] = bo1[tid]; bo2_l[tid] = bo2[tid];
    }
    __syncthreads();

    // ---- build scaled attention matrices: A = Wq^T Wk /sqrt(D), u, v, c ----
    const float isq = 0.17677669529663688f; // 1/sqrt(32)
    {
        const int i = tid & 31, jb = (tid >> 5) * 4;
        float s0 = 0.f, s1 = 0.f, s2 = 0.f, s3 = 0.f;
        #pragma unroll
        for (int d = 0; d < 32; ++d) {
            float wq = Wq_l[d * 32 + i];
            s0 += wq * Wk_l[d * 32 + jb];
            s1 += wq * Wk_l[d * 32 + jb + 1];
            s2 += wq * Wk_l[d * 32 + jb + 2];
            s3 += wq * Wk_l[d * 32 + jb + 3];
        }
        A_l[i * 32 + jb]     = s0 * isq;
        A_l[i * 32 + jb + 1] = s1 * isq;
        A_l[i * 32 + jb + 2] = s2 * isq;
        A_l[i * 32 + jb + 3] = s3 * isq;
    }
    if (tid < 32) {
        float s = 0.f;
        #pragma unroll
        for (int d = 0; d < 32; ++d) s += bq[d] * Wk_l[d * 32 + tid];
        u_l[tid] = s * isq;
    } else if (tid < 64) {
        const int i = tid - 32; float s = 0.f;
        #pragma unroll
        for (int d = 0; d < 32; ++d) s += Wq_l[d * 32 + i] * bk[d];
        v_l[i] = s * isq;
    } else if (tid == 64) {
        float s = 0.f;
        #pragma unroll
        for (int d = 0; d < 32; ++d) s += bq[d] * bk[d];
        c_l = s * isq;
    }
    __syncthreads();

    const int row  = blockIdx.x * RPB + (tid >> 1);
    const int half = tid & 1;
    if (row >= nRows) return;

    const float* __restrict__ p0 = f1 + (size_t)row * 256 + half * 128;
    const float* __restrict__ p1 = f4 + (size_t)row * 256 + half * 128;
    const float* __restrict__ p2 = fD + (size_t)row * 256 + half * 128;
    const float* __restrict__ wb = Wp_l + half * 128;

    // ---- Phase A: partial projection over this thread's 128 k-elems ----
    float acc0[32], acc1[32], acc2[32];
    #pragma unroll
    for (int d = 0; d < 32; ++d) { acc0[d] = 0.f; acc1[d] = 0.f; acc2[d] = 0.f; }

    // manual 1-deep prefetch rotation
    float4 n0a = *(const float4*)(p0),     n0b = *(const float4*)(p0 + 4);
    float4 n1a = *(const float4*)(p1),     n1b = *(const float4*)(p1 + 4);
    float4 n2a = *(const float4*)(p2),     n2b = *(const float4*)(p2 + 4);
    #pragma unroll 1
    for (int kc = 0; kc < 128; kc += 8) {
        float4 a0 = n0a, a0b = n0b, a1 = n1a, a1b = n1b, a2 = n2a, a2b = n2b;
        const int kn = (kc + 8 < 128) ? kc + 8 : kc;  // last iter reloads (L1 hit)
        n0a = *(const float4*)(p0 + kn); n0b = *(const float4*)(p0 + kn + 4);
        n1a = *(const float4*)(p1 + kn); n1b = *(const float4*)(p1 + kn + 4);
        n2a = *(const float4*)(p2 + kn); n2b = *(const float4*)(p2 + kn + 4);
        #pragma unroll
        for (int d = 0; d < 32; ++d) {
            const float* wr = wb + d * 256 + kc;
            float4 w  = *(const float4*)(wr);
            float4 w2 = *(const float4*)(wr + 4);
            acc0[d] += a0.x*w.x + a0.y*w.y + a0.z*w.z + a0.w*w.w
                     + a0b.x*w2.x + a0b.y*w2.y + a0b.z*w2.z + a0b.w*w2.w;
            acc1[d] += a1.x*w.x + a1.y*w.y + a1.z*w.z + a1.w*w.w
                     + a1b.x*w2.x + a1b.y*w2.y + a1b.z*w2.z + a1b.w*w2.w;
            acc2[d] += a2.x*w.x + a2.y*w.y + a2.z*w.z + a2.w*w.w
                     + a2b.x*w2.x + a2b.y*w2.y + a2b.z*w2.z + a2b.w*w2.w;
        }
    }

    // ---- pair reduce: both lanes get the full row dot ----
    #pragma unroll
    for (int d = 0; d < 32; ++d) {
        acc0[d] += __shfl_xor(acc0[d], 1);
        acc1[d] += __shfl_xor(acc1[d], 1);
        acc2[d] += __shfl_xor(acc2[d], 1);
    }

    // ---- relu + LayerNorm -> X[3][32] (replicated on both lanes) ----
    float X[3][32];
#define LNORM(ACC_, S_)                                                    \
    {                                                                      \
        float sum = 0.f, sq = 0.f;                                         \
        _Pragma("unroll")                                                  \
        for (int d = 0; d < 32; ++d) {                                     \
            float h = fmaxf(ACC_[d] + bp_l[d], 0.f);                       \
            ACC_[d] = h; sum += h; sq += h * h;                            \
        }                                                                  \
        float mu  = sum * 0.03125f;                                        \
        float var = sq * 0.03125f - mu * mu;                               \
        float inv = rsqrtf(var + 1e-5f);                                   \
        _Pragma("unroll")                                                  \
        for (int d = 0; d < 32; ++d)                                       \
            X[S_][d] = g_l[d] * (ACC_[d] - mu) * inv + b_l[d];             \
    }
    LNORM(acc0, 0)
    LNORM(acc1, 1)
    LNORM(acc2, 2)
#undef LNORM

    // ---- scores via A,u,v,c — each lane dots its 16-elem half ----
    const int dbase = half * 16;
    float up[3], vp[3];
    #pragma unroll
    for (int t = 0; t < 3; ++t) {
        float us = 0.f, vs = 0.f;
        #pragma unroll
        for (int e = 0; e < 16; ++e) {
            us += u_l[dbase + e] * X[t][dbase + e];
            vs += v_l[dbase + e] * X[t][dbase + e];
        }
        up[t] = us; vp[t] = vs;
    }
    float sc[3][3];
    #pragma unroll
    for (int t = 0; t < 3; ++t) {
        float Z[16];
        #pragma unroll
        for (int e = 0; e < 16; ++e) {
            const float4* ar = (const float4*)(A_l + (dbase + e) * 32);
            float z = 0.f;
            #pragma unroll
            for (int j = 0; j < 8; ++j) {
                float4 a = ar[j];
                z += DOT4(X[t], j, a);
            }
            Z[e] = z;
        }
        #pragma unroll
        for (int s = 0; s < 3; ++s) {
            float p = 0.f;
            #pragma unroll
            for (int e = 0; e < 16; ++e) p += X[s][dbase + e] * Z[e];
            sc[s][t] = p;
        }
    }
    #pragma unroll
    for (int s = 0; s < 3; ++s)
        #pragma unroll
        for (int t = 0; t < 3; ++t) {
            float p = sc[s][t] + up[t] + vp[s];
            p += __shfl_xor(p, 1);
            sc[s][t] = p + c_l;
        }

    // ---- softmax rows; g_t = (1/3) sum_s w[s][t] ----
    float g0 = 0.f, g1 = 0.f, g2 = 0.f;
    #pragma unroll
    for (int s = 0; s < 3; ++s) {
        float m  = fmaxf(sc[s][0], fmaxf(sc[s][1], sc[s][2]));
        float e0 = __expf(sc[s][0] - m), e1 = __expf(sc[s][1] - m), e2 = __expf(sc[s][2] - m);
        float r  = 1.f / (e0 + e1 + e2);
        g0 += e0 * r; g1 += e1 * r; g2 += e2 * r;
    }
    g0 *= (1.f / 3.f); g1 *= (1.f / 3.f); g2 *= (1.f / 3.f);

    // xb = g0*X0 + g1*X1 + g2*X2 (full, replicated — matvec input)
    float xb[32];
    #pragma unroll
    for (int e = 0; e < 32; ++e)
        xb[e] = g0 * X[0][e] + g1 * X[1][e] + g2 * X[2][e];

    // helper: half-matvec then pair-exchange to rebuild full vector
#define HALF_MATVEC(W_, BIAS_, IN_, OUTH_)                                 \
    _Pragma("unroll")                                                      \
    for (int i = 0; i < 16; ++i) {                                         \
        const int d = dbase + i;                                           \
        const float4* wr = (const float4*)(W_ + d * 32);                   \
        float p = BIAS_[d];                                                \
        _Pragma("unroll")                                                  \
        for (int j = 0; j < 8; ++j) {                                      \
            float4 w = wr[j];                                              \
            p += DOT4(IN_, j, w);                                          \
        }                                                                  \
        OUTH_[i] = p;                                                      \
    }
#define EXCHANGE(HALF_, FULL_)                                             \
    _Pragma("unroll")                                                      \
    for (int i = 0; i < 16; ++i) {                                         \
        float o = __shfl_xor(HALF_[i], 1);                                 \
        FULL_[dbase + i]          = HALF_[i];                              \
        FULL_[(dbase ^ 16) + i]   = o;                                     \
    }

    // pooled = xb @ Wv^T + bv
    float ph[16], pooled[32];
    HALF_MATVEC(Wv_l, bv_l, xb, ph)
    EXCHANGE(ph, pooled)

    // h1 = relu(pooled @ Wo1^T + bo1)
    float hh[16], h1[32];
    HALF_MATVEC(Wo1_l, bo1_l, pooled, hh)
    #pragma unroll
    for (int i = 0; i < 16; ++i) hh[i] = fmaxf(hh[i], 0.f);
    EXCHANGE(hh, h1)

    // out_half = h1 @ Wo2^T + bo2 + pooled  (each lane writes its 16 floats)
    float oh[16];
    HALF_MATVEC(Wo2_l, bo2_l, h1, oh)
    #pragma unroll
    for (int i = 0; i < 16; ++i) oh[i] += pooled[dbase + i];

    float4* op = (float4*)(out + (size_t)row * 32 + dbase);
    #pragma unroll
    for (int j = 0; j < 4; ++j)
        op[j] = make_float4(oh[4 * j], oh[4 * j + 1], oh[4 * j + 2], oh[4 * j + 3]);
#undef HALF_MATVEC
#undef EXCHANGE
}

extern "C" void kernel_launch(void* const* d_in, const int* in_sizes, int n_in,
                              void* d_out, int out_size, void* d_ws, size_t ws_size,
                              hipStream_t stream) {
    const float* f1   = (const float*)d_in[0];
    const float* f4   = (const float*)d_in[1];
    const float* fD   = (const float*)d_in[2];
    const float* Wp   = (const float*)d_in[3];
    const float* bp   = (const float*)d_in[4];
    const float* ln_g = (const float*)d_in[5];
    const float* ln_b = (const float*)d_in[6];
    const float* Wq   = (const float*)d_in[7];
    const float* bq   = (const float*)d_in[8];
    const float* Wk   = (const float*)d_in[9];
    const float* bk   = (const float*)d_in[10];
    const float* Wv   = (const float*)d_in[11];
    const float* bv   = (const float*)d_in[12];
    const float* Wo1  = (const float*)d_in[13];
    const float* bo1  = (const float*)d_in[14];
    const float* Wo2  = (const float*)d_in[15];
    const float* bo2  = (const float*)d_in[16];

    const int nRows  = in_sizes[0] / 256;
    const int blocks = (nRows + RPB - 1) / RPB;

    msfe_kernel<<<blocks, BLOCK, 0, stream>>>(
        f1, f4, fD, Wp, bp, ln_g, ln_b, Wq, bq, Wk, bk, Wv, bv,
        Wo1, bo1, Wo2, bo2, (float*)d_out, nRows);
}